// Round 1
// baseline (149.754 us; speedup 1.0000x reference)
//
#include <hip/hip_runtime.h>
#include <hip/hip_bf16.h>

typedef short short8 __attribute__((ext_vector_type(8)));
typedef float f32x4 __attribute__((ext_vector_type(4)));

#define MFMA16(a, b, c) __builtin_amdgcn_mfma_f32_16x16x32_bf16(a, b, c, 0, 0, 0)

__device__ __forceinline__ unsigned short f2bf(float f) {
    unsigned int u = __float_as_uint(f);
    unsigned int r = (u + 0x7fffu + ((u >> 16) & 1u)) >> 16;
    return (unsigned short)r;
}

// ---------------- prep: convert weights fp32 -> bf16 ----------------
__global__ __launch_bounds__(256) void k_wcvt(const float* __restrict__ qkv_w,
                                              const float* __restrict__ proj_w,
                                              unsigned short* __restrict__ wqb,
                                              unsigned short* __restrict__ pwb) {
    int i = (blockIdx.x * 256 + threadIdx.x) * 4;
    const int NQ = 768 * 256;
    const float* src;
    unsigned short* dst;
    if (i < NQ) { src = qkv_w + i; dst = wqb + i; }
    else        { src = proj_w + (i - NQ); dst = pwb + (i - NQ); }
    float4 v = *reinterpret_cast<const float4*>(src);
    ushort4 p;
    p.x = f2bf(v.x); p.y = f2bf(v.y); p.z = f2bf(v.z); p.w = f2bf(v.w);
    *reinterpret_cast<ushort4*>(dst) = p;
}

// ---------------- prep: transpose x [256][4096] fp32 -> xT [4096][256] bf16 ----------------
__global__ __launch_bounds__(256) void k_xt(const float* __restrict__ x,
                                            unsigned short* __restrict__ xtb) {
    __shared__ float lds[64][65];
    int nt = blockIdx.x;   // 0..63 n-tile
    int ct = blockIdx.y;   // 0..3  c-tile
    int t = threadIdx.x;
    {
        int cc = t >> 2, nseg = t & 3;
        const float* src = x + (ct * 64 + cc) * 4096 + nt * 64 + nseg * 16;
#pragma unroll
        for (int k2 = 0; k2 < 4; ++k2) {
            float4 v = *reinterpret_cast<const float4*>(src + 4 * k2);
            lds[cc][nseg * 16 + 4 * k2 + 0] = v.x;
            lds[cc][nseg * 16 + 4 * k2 + 1] = v.y;
            lds[cc][nseg * 16 + 4 * k2 + 2] = v.z;
            lds[cc][nseg * 16 + 4 * k2 + 3] = v.w;
        }
    }
    __syncthreads();
    {
        int nn = t >> 2, seg = t & 3;
        unsigned short o[16];
#pragma unroll
        for (int j = 0; j < 16; ++j) o[j] = f2bf(lds[seg * 16 + j][nn]);
        unsigned short* dst = xtb + (nt * 64 + nn) * 256 + ct * 64 + seg * 16;
#pragma unroll
        for (int k2 = 0; k2 < 4; ++k2) {
            ushort4 p;
            p.x = o[4 * k2 + 0]; p.y = o[4 * k2 + 1]; p.z = o[4 * k2 + 2]; p.w = o[4 * k2 + 3];
            *reinterpret_cast<ushort4*>(dst + 4 * k2) = p;
        }
    }
}

// ---------------- QKV GEMM: [768][256] x [256][4096] -> scatter q/k/v bf16 ----------------
// q,k stored [h][n][32] (q pre-scaled by hd^-0.5), v stored [h*32+d][n] (natural)
__global__ __launch_bounds__(256) void k_qkv(const unsigned short* __restrict__ wqb,
                                             const unsigned short* __restrict__ xtb,
                                             unsigned short* __restrict__ qws,
                                             unsigned short* __restrict__ kws,
                                             unsigned short* __restrict__ vws) {
    int nt = blockIdx.x;           // 0..63 : n tile of 64
    int ot = blockIdx.y;           // 0..5  : o tile of 128
    int w = threadIdx.x >> 6;
    int l = threadIdx.x & 63;
    int lr = l & 15, lg = l >> 4;
    int obase = ot * 128 + w * 32;
    int nbase = nt * 64;

    f32x4 acc[2][4];
#pragma unroll
    for (int mi = 0; mi < 2; ++mi)
#pragma unroll
        for (int ni = 0; ni < 4; ++ni) acc[mi][ni] = (f32x4){0.f, 0.f, 0.f, 0.f};

#pragma unroll
    for (int ks = 0; ks < 8; ++ks) {
        short8 a[2], b[4];
#pragma unroll
        for (int mi = 0; mi < 2; ++mi)
            a[mi] = *reinterpret_cast<const short8*>(wqb + (obase + mi * 16 + lr) * 256 + ks * 32 + lg * 8);
#pragma unroll
        for (int ni = 0; ni < 4; ++ni)
            b[ni] = *reinterpret_cast<const short8*>(xtb + (nbase + ni * 16 + lr) * 256 + ks * 32 + lg * 8);
#pragma unroll
        for (int mi = 0; mi < 2; ++mi)
#pragma unroll
            for (int ni = 0; ni < 4; ++ni)
                acc[mi][ni] = MFMA16(a[mi], b[ni], acc[mi][ni]);
    }

#pragma unroll
    for (int mi = 0; mi < 2; ++mi) {
        int o0 = obase + mi * 16 + lg * 4;   // rows o0..o0+3 (4 consecutive d)
#pragma unroll
        for (int ni = 0; ni < 4; ++ni) {
            int n = nbase + ni * 16 + lr;
            f32x4 v = acc[mi][ni];
            if (o0 < 512) {
                float sc = (o0 < 256) ? 0.17677669529663687f : 1.0f;
                unsigned short* base = (o0 < 256) ? qws : kws;
                int oo = o0 & 255;
                int h = oo >> 5, d0 = oo & 31;
                ushort4 pk;
                pk.x = f2bf(v[0] * sc); pk.y = f2bf(v[1] * sc);
                pk.z = f2bf(v[2] * sc); pk.w = f2bf(v[3] * sc);
                *reinterpret_cast<ushort4*>(base + h * 131072 + n * 32 + d0) = pk;
            } else {
                int oo = o0 - 512;
#pragma unroll
                for (int r = 0; r < 4; ++r) vws[(oo + r) * 4096 + n] = f2bf(v[r]);
            }
        }
    }
}

// ---------------- flash attention: per (head, 64-row q tile) ----------------
__global__ __launch_bounds__(256) void k_attn(const unsigned short* __restrict__ qws,
                                              const unsigned short* __restrict__ kws,
                                              const unsigned short* __restrict__ vws,
                                              unsigned short* __restrict__ ao) {
    __shared__ __align__(16) short kt[64 * 40];       // [m][d] pad->40
    __shared__ __align__(16) short vt[32 * 72];       // [d][m] pad->72
    __shared__ __align__(16) short pt[4][16 * 72];    // per-wave P [qrow][m] pad->72

    int qt = blockIdx.x, h = blockIdx.y;
    int t = threadIdx.x;
    int w = t >> 6, l = t & 63, lr = l & 15, lg = l >> 4;

    const unsigned short* qh = qws + h * 131072;
    const unsigned short* kh = kws + h * 131072;
    const unsigned short* vh = vws + h * 32 * 4096;

    int qrow0 = qt * 64 + w * 16;
    short8 aq = *reinterpret_cast<const short8*>(qh + (qrow0 + lr) * 32 + lg * 8);

    f32x4 oacc[2];
    oacc[0] = (f32x4){0.f, 0.f, 0.f, 0.f};
    oacc[1] = (f32x4){0.f, 0.f, 0.f, 0.f};
    float mrun[4], lrun[4];
#pragma unroll
    for (int r = 0; r < 4; ++r) { mrun[r] = -1e30f; lrun[r] = 0.f; }

    short* myp = pt[w];

    for (int mt = 0; mt < 64; ++mt) {
        __syncthreads();
        // stage K tile [64][32] -> kt[m][d], V tile [32][64] -> vt[d][m]
        {
            int row = t >> 2, part = t & 3;
            *reinterpret_cast<short8*>(&kt[row * 40 + part * 8]) =
                *reinterpret_cast<const short8*>(kh + (mt * 64 + row) * 32 + part * 8);
            int vrow = t >> 3, seg = t & 7;
            *reinterpret_cast<short8*>(&vt[vrow * 72 + seg * 8]) =
                *reinterpret_cast<const short8*>(vh + vrow * 4096 + mt * 64 + seg * 8);
        }
        __syncthreads();

        // S = Q K^T (scale folded into Q)
        f32x4 s[4];
        const f32x4 z4 = (f32x4){0.f, 0.f, 0.f, 0.f};
#pragma unroll
        for (int sub = 0; sub < 4; ++sub) {
            short8 bk = *reinterpret_cast<const short8*>(&kt[(sub * 16 + lr) * 40 + lg * 8]);
            s[sub] = MFMA16(aq, bk, z4);
        }

        // online softmax per q-row (4 rows per lane-group, reg r)
#pragma unroll
        for (int r = 0; r < 4; ++r) {
            float m4 = fmaxf(fmaxf(s[0][r], s[1][r]), fmaxf(s[2][r], s[3][r]));
            m4 = fmaxf(m4, __shfl_xor(m4, 1));
            m4 = fmaxf(m4, __shfl_xor(m4, 2));
            m4 = fmaxf(m4, __shfl_xor(m4, 4));
            m4 = fmaxf(m4, __shfl_xor(m4, 8));
            float mn = fmaxf(mrun[r], m4);
            float rs = __expf(mrun[r] - mn);
            mrun[r] = mn;
            float sum = 0.f;
#pragma unroll
            for (int sub = 0; sub < 4; ++sub) {
                float p = __expf(s[sub][r] - mn);
                s[sub][r] = p;
                sum += p;
            }
            sum += __shfl_xor(sum, 1);
            sum += __shfl_xor(sum, 2);
            sum += __shfl_xor(sum, 4);
            sum += __shfl_xor(sum, 8);
            lrun[r] = lrun[r] * rs + sum;
            oacc[0][r] *= rs;
            oacc[1][r] *= rs;
        }

        // P -> LDS (bf16), C-layout -> A-layout bounce
#pragma unroll
        for (int sub = 0; sub < 4; ++sub)
#pragma unroll
            for (int r = 0; r < 4; ++r)
                myp[(lg * 4 + r) * 72 + sub * 16 + lr] = (short)f2bf(s[sub][r]);

        // O += P V
#pragma unroll
        for (int kc = 0; kc < 2; ++kc) {
            short8 pa = *reinterpret_cast<const short8*>(&myp[lr * 72 + kc * 32 + lg * 8]);
#pragma unroll
            for (int dsub = 0; dsub < 2; ++dsub) {
                short8 vb = *reinterpret_cast<const short8*>(&vt[(dsub * 16 + lr) * 72 + kc * 32 + lg * 8]);
                oacc[dsub] = MFMA16(pa, vb, oacc[dsub]);
            }
        }
    }

    // epilogue: ao[n][c] bf16, normalized
#pragma unroll
    for (int dsub = 0; dsub < 2; ++dsub)
#pragma unroll
        for (int r = 0; r < 4; ++r) {
            int n = qrow0 + lg * 4 + r;
            int c = h * 32 + dsub * 16 + lr;
            ao[n * 256 + c] = f2bf(oacc[dsub][r] / lrun[r]);
        }
}

// ---------------- proj GEMM: [256][256] x ao^T + bias -> out fp32 [256][4096] ----------------
__global__ __launch_bounds__(256) void k_proj(const unsigned short* __restrict__ pwb,
                                              const unsigned short* __restrict__ ao,
                                              const float* __restrict__ bias,
                                              float* __restrict__ out) {
    int nt = blockIdx.x;   // 0..63
    int ot = blockIdx.y;   // 0..1
    int w = threadIdx.x >> 6;
    int l = threadIdx.x & 63;
    int lr = l & 15, lg = l >> 4;
    int obase = ot * 128 + w * 32;
    int nbase = nt * 64;

    f32x4 acc[2][4];
#pragma unroll
    for (int mi = 0; mi < 2; ++mi)
#pragma unroll
        for (int ni = 0; ni < 4; ++ni) acc[mi][ni] = (f32x4){0.f, 0.f, 0.f, 0.f};

#pragma unroll
    for (int ks = 0; ks < 8; ++ks) {
        short8 a[2], b[4];
#pragma unroll
        for (int mi = 0; mi < 2; ++mi)
            a[mi] = *reinterpret_cast<const short8*>(pwb + (obase + mi * 16 + lr) * 256 + ks * 32 + lg * 8);
#pragma unroll
        for (int ni = 0; ni < 4; ++ni)
            b[ni] = *reinterpret_cast<const short8*>(ao + (nbase + ni * 16 + lr) * 256 + ks * 32 + lg * 8);
#pragma unroll
        for (int mi = 0; mi < 2; ++mi)
#pragma unroll
            for (int ni = 0; ni < 4; ++ni)
                acc[mi][ni] = MFMA16(a[mi], b[ni], acc[mi][ni]);
    }

#pragma unroll
    for (int mi = 0; mi < 2; ++mi) {
        int o0 = obase + mi * 16 + lg * 4;
        float b0 = bias[o0 + 0], b1 = bias[o0 + 1], b2 = bias[o0 + 2], b3 = bias[o0 + 3];
#pragma unroll
        for (int ni = 0; ni < 4; ++ni) {
            int n = nbase + ni * 16 + lr;
            out[(o0 + 0) * 4096 + n] = acc[mi][ni][0] + b0;
            out[(o0 + 1) * 4096 + n] = acc[mi][ni][1] + b1;
            out[(o0 + 2) * 4096 + n] = acc[mi][ni][2] + b2;
            out[(o0 + 3) * 4096 + n] = acc[mi][ni][3] + b3;
        }
    }
}

extern "C" void kernel_launch(void* const* d_in, const int* in_sizes, int n_in,
                              void* d_out, int out_size, void* d_ws, size_t ws_size,
                              hipStream_t stream) {
    const float* x      = (const float*)d_in[0];
    const float* qkv_w  = (const float*)d_in[1];
    const float* proj_w = (const float*)d_in[2];
    const float* proj_b = (const float*)d_in[3];
    float* out = (float*)d_out;

    char* ws = (char*)d_ws;
    unsigned short* wqb = (unsigned short*)(ws + 0);         // 768*256*2   = 393216
    unsigned short* pwb = (unsigned short*)(ws + 393216);    // 256*256*2   = 131072
    unsigned short* xtb = (unsigned short*)(ws + 524288);    // 4096*256*2  = 2097152
    unsigned short* qws = (unsigned short*)(ws + 2621440);   // 8*4096*32*2 = 2097152
    unsigned short* kws = (unsigned short*)(ws + 4718592);   // 2097152
    unsigned short* vws = (unsigned short*)(ws + 6815744);   // 2097152
    unsigned short* ao  = (unsigned short*)(ws + 8912896);   // 4096*256*2  = 2097152

    k_wcvt<<<256, 256, 0, stream>>>(qkv_w, proj_w, wqb, pwb);
    k_xt<<<dim3(64, 4), 256, 0, stream>>>(x, xtb);
    k_qkv<<<dim3(64, 6), 256, 0, stream>>>(wqb, xtb, qws, kws, vws);
    k_attn<<<dim3(64, 8), 256, 0, stream>>>(qws, kws, vws, ao);
    k_proj<<<dim3(64, 2), 256, 0, stream>>>(pwb, ao, proj_b, out);
}

// Round 2
// 85.866 us; speedup vs baseline: 1.7440x; 1.7440x over previous
//
#include <hip/hip_runtime.h>
#include <hip/hip_bf16.h>

typedef short short8 __attribute__((ext_vector_type(8)));
typedef float f32x4 __attribute__((ext_vector_type(4)));
typedef unsigned int u32x4 __attribute__((ext_vector_type(4)));

#define MFMA16(a, b, c) __builtin_amdgcn_mfma_f32_16x16x32_bf16(a, b, c, 0, 0, 0)

__device__ __forceinline__ unsigned short f2bf(float f) {
    unsigned int u = __float_as_uint(f);
    unsigned int r = (u + 0x7fffu + ((u >> 16) & 1u)) >> 16;
    return (unsigned short)r;
}

__device__ __forceinline__ float fexp2(float x) {
#if __has_builtin(__builtin_amdgcn_exp2f)
    return __builtin_amdgcn_exp2f(x);
#else
    return exp2f(x);
#endif
}

__device__ __forceinline__ unsigned int cvtpk(float lo, float hi) {
    unsigned int r;
    asm("v_cvt_pk_bf16_f32 %0, %1, %2" : "=v"(r) : "v"(lo), "v"(hi));
    return r;
}

__device__ __forceinline__ float hmax4(f32x4 a) { return fmaxf(fmaxf(a[0], a[1]), fmaxf(a[2], a[3])); }
__device__ __forceinline__ float hsum4(f32x4 a) { return (a[0] + a[1]) + (a[2] + a[3]); }

// q scale: hd^-0.5 * log2(e)  (softmax done in base-2 domain)
#define QSC (0.17677669529663687f * 1.4426950408889634f)

// ---------------- prep: convert weights fp32 -> bf16 ----------------
__global__ __launch_bounds__(256) void k_wcvt(const float* __restrict__ qkv_w,
                                              const float* __restrict__ proj_w,
                                              unsigned short* __restrict__ wqb,
                                              unsigned short* __restrict__ pwb) {
    int i = (blockIdx.x * 256 + threadIdx.x) * 4;
    const int NQ = 768 * 256;
    const float* src;
    unsigned short* dst;
    if (i < NQ) { src = qkv_w + i; dst = wqb + i; }
    else        { src = proj_w + (i - NQ); dst = pwb + (i - NQ); }
    float4 v = *reinterpret_cast<const float4*>(src);
    ushort4 p;
    p.x = f2bf(v.x); p.y = f2bf(v.y); p.z = f2bf(v.z); p.w = f2bf(v.w);
    *reinterpret_cast<ushort4*>(dst) = p;
}

// ---------------- prep: transpose x [256][4096] fp32 -> xT [4096][256] bf16 ----------------
__global__ __launch_bounds__(256) void k_xt(const float* __restrict__ x,
                                            unsigned short* __restrict__ xtb) {
    __shared__ float lds[64][65];
    int nt = blockIdx.x;   // 0..63 n-tile
    int ct = blockIdx.y;   // 0..3  c-tile
    int t = threadIdx.x;
    {
        int cc = t >> 2, nseg = t & 3;
        const float* src = x + (ct * 64 + cc) * 4096 + nt * 64 + nseg * 16;
#pragma unroll
        for (int k2 = 0; k2 < 4; ++k2) {
            float4 v = *reinterpret_cast<const float4*>(src + 4 * k2);
            lds[cc][nseg * 16 + 4 * k2 + 0] = v.x;
            lds[cc][nseg * 16 + 4 * k2 + 1] = v.y;
            lds[cc][nseg * 16 + 4 * k2 + 2] = v.z;
            lds[cc][nseg * 16 + 4 * k2 + 3] = v.w;
        }
    }
    __syncthreads();
    {
        int nn = t >> 2, seg = t & 3;
        unsigned short o[16];
#pragma unroll
        for (int j = 0; j < 16; ++j) o[j] = f2bf(lds[seg * 16 + j][nn]);
        unsigned short* dst = xtb + (nt * 64 + nn) * 256 + ct * 64 + seg * 16;
#pragma unroll
        for (int k2 = 0; k2 < 4; ++k2) {
            ushort4 p;
            p.x = o[4 * k2 + 0]; p.y = o[4 * k2 + 1]; p.z = o[4 * k2 + 2]; p.w = o[4 * k2 + 3];
            *reinterpret_cast<ushort4*>(dst + 4 * k2) = p;
        }
    }
}

// ---------------- QKV GEMM: [768][256] x [256][4096] -> scatter q/k/v bf16 ----------------
// q,k stored [h][n][32] (q pre-scaled by hd^-0.5*log2e), v stored [h*32+d][n]
__global__ __launch_bounds__(256) void k_qkv(const unsigned short* __restrict__ wqb,
                                             const unsigned short* __restrict__ xtb,
                                             unsigned short* __restrict__ qws,
                                             unsigned short* __restrict__ kws,
                                             unsigned short* __restrict__ vws) {
    int nt = blockIdx.x;           // 0..63 : n tile of 64
    int ot = blockIdx.y;           // 0..5  : o tile of 128
    int w = threadIdx.x >> 6;
    int l = threadIdx.x & 63;
    int lr = l & 15, lg = l >> 4;
    int obase = ot * 128 + w * 32;
    int nbase = nt * 64;

    f32x4 acc[2][4];
#pragma unroll
    for (int mi = 0; mi < 2; ++mi)
#pragma unroll
        for (int ni = 0; ni < 4; ++ni) acc[mi][ni] = (f32x4){0.f, 0.f, 0.f, 0.f};

#pragma unroll
    for (int ks = 0; ks < 8; ++ks) {
        short8 a[2], b[4];
#pragma unroll
        for (int mi = 0; mi < 2; ++mi)
            a[mi] = *reinterpret_cast<const short8*>(wqb + (obase + mi * 16 + lr) * 256 + ks * 32 + lg * 8);
#pragma unroll
        for (int ni = 0; ni < 4; ++ni)
            b[ni] = *reinterpret_cast<const short8*>(xtb + (nbase + ni * 16 + lr) * 256 + ks * 32 + lg * 8);
#pragma unroll
        for (int mi = 0; mi < 2; ++mi)
#pragma unroll
            for (int ni = 0; ni < 4; ++ni)
                acc[mi][ni] = MFMA16(a[mi], b[ni], acc[mi][ni]);
    }

#pragma unroll
    for (int mi = 0; mi < 2; ++mi) {
        int o0 = obase + mi * 16 + lg * 4;   // rows o0..o0+3
#pragma unroll
        for (int ni = 0; ni < 4; ++ni) {
            int n = nbase + ni * 16 + lr;
            f32x4 v = acc[mi][ni];
            if (o0 < 512) {
                float sc = (o0 < 256) ? QSC : 1.0f;
                unsigned short* base = (o0 < 256) ? qws : kws;
                int oo = o0 & 255;
                int h = oo >> 5, d0 = oo & 31;
                ushort4 pk;
                pk.x = f2bf(v[0] * sc); pk.y = f2bf(v[1] * sc);
                pk.z = f2bf(v[2] * sc); pk.w = f2bf(v[3] * sc);
                *reinterpret_cast<ushort4*>(base + h * 131072 + n * 32 + d0) = pk;
            } else {
                int oo = o0 - 512;
#pragma unroll
                for (int r = 0; r < 4; ++r) vws[(oo + r) * 4096 + n] = f2bf(v[r]);
            }
        }
    }
}

// ---------------- flash attention, LDS-free, split-K ----------------
// Wave handles 32 q-rows; S computed transposed (A=K perm, B=Q) so each lane
// owns 2 q-rows fully; P-frag for PV is a pure in-lane pack. O computed as
// O^T = V^T P^T. Partials (O', m, l) per split -> combine kernel.
__global__ __launch_bounds__(256, 4) void k_attn(const unsigned short* __restrict__ qws,
                                                 const unsigned short* __restrict__ kws,
                                                 const unsigned short* __restrict__ vws,
                                                 float* __restrict__ opart,
                                                 float* __restrict__ oml) {
    int qs = blockIdx.x;   // 0..31 : 128-row super-tile
    int h  = blockIdx.y;   // 0..7
    int sp = blockIdx.z;   // 0..3  : key split (1024 keys each)
    int t = threadIdx.x;
    int w = t >> 6, l = t & 63, lr = l & 15, lg = l >> 4;

    const unsigned short* qh = qws + h * 131072;
    const unsigned short* kh = kws + h * 131072;
    const unsigned short* vh = vws + h * 131072;

    int qb = qs * 128 + w * 32;
    short8 bq0 = *reinterpret_cast<const short8*>(qh + (qb + lr) * 32 + lg * 8);
    short8 bq1 = *reinterpret_cast<const short8*>(qh + (qb + 16 + lr) * 32 + lg * 8);

    f32x4 o00 = {0.f,0.f,0.f,0.f}, o01 = o00, o10 = o00, o11 = o00; // o[j][dsub]
    float m0 = -1e30f, m1 = -1e30f, l0 = 0.f, l1 = 0.f;

    // K A-frag key-row permutation base: rows {8*(lr>>2)+(lr&3)} + {0,4,32,36}
    int krow = 8 * (lr >> 2) + (lr & 3);
    const unsigned short* kp = kh + krow * 32 + lg * 8;
    const unsigned short* vp = vh + lr * 4096 + lg * 8;

    int mt0 = sp * 16, mt1 = mt0 + 16;
    short8 ka0, ka1, ka2, ka3;
    {
        const unsigned short* b = kp + mt0 * 2048;
        ka0 = *reinterpret_cast<const short8*>(b);
        ka1 = *reinterpret_cast<const short8*>(b + 128);
        ka2 = *reinterpret_cast<const short8*>(b + 1024);
        ka3 = *reinterpret_cast<const short8*>(b + 1152);
    }

    for (int mt = mt0; mt < mt1; ++mt) {
        // V frags: A=V^T rows d, issue early to overlap with softmax
        const unsigned short* vb = vp + mt * 64;
        short8 va00 = *reinterpret_cast<const short8*>(vb);
        short8 va01 = *reinterpret_cast<const short8*>(vb + 32);
        short8 va10 = *reinterpret_cast<const short8*>(vb + 65536);
        short8 va11 = *reinterpret_cast<const short8*>(vb + 65536 + 32);

        const f32x4 z = {0.f, 0.f, 0.f, 0.f};
        f32x4 s00 = MFMA16(ka0, bq0, z);
        f32x4 s01 = MFMA16(ka1, bq0, z);
        f32x4 s02 = MFMA16(ka2, bq0, z);
        f32x4 s03 = MFMA16(ka3, bq0, z);
        f32x4 s10 = MFMA16(ka0, bq1, z);
        f32x4 s11 = MFMA16(ka1, bq1, z);
        f32x4 s12 = MFMA16(ka2, bq1, z);
        f32x4 s13 = MFMA16(ka3, bq1, z);

        // prefetch next K tile (clamped;覆盖 latency under softmax)
        {
            int mtn = (mt + 1 < mt1) ? (mt + 1) : mt0;
            const unsigned short* b = kp + mtn * 2048;
            ka0 = *reinterpret_cast<const short8*>(b);
            ka1 = *reinterpret_cast<const short8*>(b + 128);
            ka2 = *reinterpret_cast<const short8*>(b + 1024);
            ka3 = *reinterpret_cast<const short8*>(b + 1152);
        }

        // ---- online softmax, per-lane rows (j=0: q=qb+lr, j=1: q=qb+16+lr)
        float tm0 = fmaxf(fmaxf(hmax4(s00), hmax4(s01)), fmaxf(hmax4(s02), hmax4(s03)));
        tm0 = fmaxf(tm0, __shfl_xor(tm0, 16));
        tm0 = fmaxf(tm0, __shfl_xor(tm0, 32));
        float mn0 = fmaxf(m0, tm0);
        float rs0 = fexp2(m0 - mn0);
        m0 = mn0;
#pragma unroll
        for (int e = 0; e < 4; ++e) {
            s00[e] = fexp2(s00[e] - mn0); s01[e] = fexp2(s01[e] - mn0);
            s02[e] = fexp2(s02[e] - mn0); s03[e] = fexp2(s03[e] - mn0);
        }
        float ts0 = (hsum4(s00) + hsum4(s01)) + (hsum4(s02) + hsum4(s03));
        ts0 += __shfl_xor(ts0, 16);
        ts0 += __shfl_xor(ts0, 32);
        l0 = l0 * rs0 + ts0;
        o00 *= rs0; o01 *= rs0;

        float tm1 = fmaxf(fmaxf(hmax4(s10), hmax4(s11)), fmaxf(hmax4(s12), hmax4(s13)));
        tm1 = fmaxf(tm1, __shfl_xor(tm1, 16));
        tm1 = fmaxf(tm1, __shfl_xor(tm1, 32));
        float mn1 = fmaxf(m1, tm1);
        float rs1 = fexp2(m1 - mn1);
        m1 = mn1;
#pragma unroll
        for (int e = 0; e < 4; ++e) {
            s10[e] = fexp2(s10[e] - mn1); s11[e] = fexp2(s11[e] - mn1);
            s12[e] = fexp2(s12[e] - mn1); s13[e] = fexp2(s13[e] - mn1);
        }
        float ts1 = (hsum4(s10) + hsum4(s11)) + (hsum4(s12) + hsum4(s13));
        ts1 += __shfl_xor(ts1, 16);
        ts1 += __shfl_xor(ts1, 32);
        l1 = l1 * rs1 + ts1;
        o10 *= rs1; o11 *= rs1;

        // ---- P -> bf16 B-frags, pure in-lane packing
        union { u32x4 u; short8 s8; } p00, p01, p10, p11;
        p00.u[0] = cvtpk(s00[0], s00[1]); p00.u[1] = cvtpk(s00[2], s00[3]);
        p00.u[2] = cvtpk(s01[0], s01[1]); p00.u[3] = cvtpk(s01[2], s01[3]);
        p01.u[0] = cvtpk(s02[0], s02[1]); p01.u[1] = cvtpk(s02[2], s02[3]);
        p01.u[2] = cvtpk(s03[0], s03[1]); p01.u[3] = cvtpk(s03[2], s03[3]);
        p10.u[0] = cvtpk(s10[0], s10[1]); p10.u[1] = cvtpk(s10[2], s10[3]);
        p10.u[2] = cvtpk(s11[0], s11[1]); p10.u[3] = cvtpk(s11[2], s11[3]);
        p11.u[0] = cvtpk(s12[0], s12[1]); p11.u[1] = cvtpk(s12[2], s12[3]);
        p11.u[2] = cvtpk(s13[0], s13[1]); p11.u[3] = cvtpk(s13[2], s13[3]);

        // ---- O^T += V^T P^T
        o00 = MFMA16(va00, p00.s8, o00);
        o00 = MFMA16(va01, p01.s8, o00);
        o01 = MFMA16(va10, p00.s8, o01);
        o01 = MFMA16(va11, p01.s8, o01);
        o10 = MFMA16(va00, p10.s8, o10);
        o10 = MFMA16(va01, p11.s8, o10);
        o11 = MFMA16(va10, p10.s8, o11);
        o11 = MFMA16(va11, p11.s8, o11);
    }

    // ---- store partials: O'[q][d] f32 + (m,l)
#pragma unroll
    for (int j = 0; j < 2; ++j) {
        int q = qb + j * 16 + lr;
        float* ob = opart + ((h * 4096 + q) * 4 + sp) * 32;
        f32x4 oa = (j == 0) ? o00 : o10;
        f32x4 obv = (j == 0) ? o01 : o11;
        *reinterpret_cast<f32x4*>(ob + lg * 4) = oa;
        *reinterpret_cast<f32x4*>(ob + 16 + lg * 4) = obv;
        float2 mlv;
        mlv.x = (j == 0) ? m0 : m1;
        mlv.y = (j == 0) ? l0 : l1;
        *reinterpret_cast<float2*>(oml + ((h * 4096 + q) * 4 + sp) * 2) = mlv; // lg-dup, identical
    }
}

// ---------------- combine split-K partials -> ao bf16 [n][256] ----------------
__global__ __launch_bounds__(256) void k_comb(const float* __restrict__ opart,
                                              const float* __restrict__ oml,
                                              unsigned short* __restrict__ ao) {
    int t = blockIdx.x * 256 + threadIdx.x;  // 131072 threads
    int hq = t >> 2;                         // 0..32767
    int dg = (t & 3) * 8;                    // d base
    const float* mlb = oml + hq * 8;
    float4 a = *reinterpret_cast<const float4*>(mlb);
    float4 b = *reinterpret_cast<const float4*>(mlb + 4);
    float ms = fmaxf(fmaxf(a.x, a.z), fmaxf(b.x, b.z));
    float w0 = fexp2(a.x - ms), w1 = fexp2(a.z - ms);
    float w2 = fexp2(b.x - ms), w3 = fexp2(b.z - ms);
    float lsum = w0 * a.y + w1 * a.w + w2 * b.y + w3 * b.w;
    float inv = 1.0f / lsum;

    const float* ob = opart + hq * 128 + dg;
    f32x4 acc0, acc1;
    {
        f32x4 v0 = *reinterpret_cast<const f32x4*>(ob);
        f32x4 v1 = *reinterpret_cast<const f32x4*>(ob + 32);
        f32x4 v2 = *reinterpret_cast<const f32x4*>(ob + 64);
        f32x4 v3 = *reinterpret_cast<const f32x4*>(ob + 96);
        acc0 = v0 * w0 + v1 * w1 + v2 * w2 + v3 * w3;
        v0 = *reinterpret_cast<const f32x4*>(ob + 4);
        v1 = *reinterpret_cast<const f32x4*>(ob + 36);
        v2 = *reinterpret_cast<const f32x4*>(ob + 68);
        v3 = *reinterpret_cast<const f32x4*>(ob + 100);
        acc1 = v0 * w0 + v1 * w1 + v2 * w2 + v3 * w3;
    }
    int h = hq >> 12, q = hq & 4095;
    unsigned short* dst = ao + q * 256 + h * 32 + dg;
    ushort4 pk;
    pk.x = f2bf(acc0[0] * inv); pk.y = f2bf(acc0[1] * inv);
    pk.z = f2bf(acc0[2] * inv); pk.w = f2bf(acc0[3] * inv);
    *reinterpret_cast<ushort4*>(dst) = pk;
    pk.x = f2bf(acc1[0] * inv); pk.y = f2bf(acc1[1] * inv);
    pk.z = f2bf(acc1[2] * inv); pk.w = f2bf(acc1[3] * inv);
    *reinterpret_cast<ushort4*>(dst + 4) = pk;
}

// ---------------- proj GEMM: [256][256] x ao^T + bias -> out fp32 [256][4096] ----------------
__global__ __launch_bounds__(256) void k_proj(const unsigned short* __restrict__ pwb,
                                              const unsigned short* __restrict__ ao,
                                              const float* __restrict__ bias,
                                              float* __restrict__ out) {
    int nt = blockIdx.x;   // 0..63
    int ot = blockIdx.y;   // 0..1
    int w = threadIdx.x >> 6;
    int l = threadIdx.x & 63;
    int lr = l & 15, lg = l >> 4;
    int obase = ot * 128 + w * 32;
    int nbase = nt * 64;

    f32x4 acc[2][4];
#pragma unroll
    for (int mi = 0; mi < 2; ++mi)
#pragma unroll
        for (int ni = 0; ni < 4; ++ni) acc[mi][ni] = (f32x4){0.f, 0.f, 0.f, 0.f};

#pragma unroll
    for (int ks = 0; ks < 8; ++ks) {
        short8 a[2], b[4];
#pragma unroll
        for (int mi = 0; mi < 2; ++mi)
            a[mi] = *reinterpret_cast<const short8*>(pwb + (obase + mi * 16 + lr) * 256 + ks * 32 + lg * 8);
#pragma unroll
        for (int ni = 0; ni < 4; ++ni)
            b[ni] = *reinterpret_cast<const short8*>(ao + (nbase + ni * 16 + lr) * 256 + ks * 32 + lg * 8);
#pragma unroll
        for (int mi = 0; mi < 2; ++mi)
#pragma unroll
            for (int ni = 0; ni < 4; ++ni)
                acc[mi][ni] = MFMA16(a[mi], b[ni], acc[mi][ni]);
    }

#pragma unroll
    for (int mi = 0; mi < 2; ++mi) {
        int o0 = obase + mi * 16 + lg * 4;
        float b0 = bias[o0 + 0], b1 = bias[o0 + 1], b2 = bias[o0 + 2], b3 = bias[o0 + 3];
#pragma unroll
        for (int ni = 0; ni < 4; ++ni) {
            int n = nbase + ni * 16 + lr;
            out[(o0 + 0) * 4096 + n] = acc[mi][ni][0] + b0;
            out[(o0 + 1) * 4096 + n] = acc[mi][ni][1] + b1;
            out[(o0 + 2) * 4096 + n] = acc[mi][ni][2] + b2;
            out[(o0 + 3) * 4096 + n] = acc[mi][ni][3] + b3;
        }
    }
}

extern "C" void kernel_launch(void* const* d_in, const int* in_sizes, int n_in,
                              void* d_out, int out_size, void* d_ws, size_t ws_size,
                              hipStream_t stream) {
    const float* x      = (const float*)d_in[0];
    const float* qkv_w  = (const float*)d_in[1];
    const float* proj_w = (const float*)d_in[2];
    const float* proj_b = (const float*)d_in[3];
    float* out = (float*)d_out;

    char* ws = (char*)d_ws;
    unsigned short* wqb = (unsigned short*)(ws + 0);         // 768*256*2   = 393216
    unsigned short* pwb = (unsigned short*)(ws + 393216);    // 256*256*2   = 131072
    unsigned short* xtb = (unsigned short*)(ws + 524288);    // 4096*256*2  = 2097152
    unsigned short* qws = (unsigned short*)(ws + 2621440);   // 8*4096*32*2 = 2097152
    unsigned short* kws = (unsigned short*)(ws + 4718592);   // 2097152
    unsigned short* vws = (unsigned short*)(ws + 6815744);   // 2097152
    unsigned short* ao  = (unsigned short*)(ws + 8912896);   // 4096*256*2  = 2097152
    float* opart        = (float*)(ws + 11010048);           // 8*4096*4*32*4 = 16777216
    float* oml          = (float*)(ws + 27787264);           // 8*4096*4*2*4  = 1048576

    k_wcvt<<<256, 256, 0, stream>>>(qkv_w, proj_w, wqb, pwb);
    k_xt<<<dim3(64, 4), 256, 0, stream>>>(x, xtb);
    k_qkv<<<dim3(64, 6), 256, 0, stream>>>(wqb, xtb, qws, kws, vws);
    k_attn<<<dim3(32, 8, 4), 256, 0, stream>>>(qws, kws, vws, opart, oml);
    k_comb<<<512, 256, 0, stream>>>(opart, oml, ao);
    k_proj<<<dim3(64, 2), 256, 0, stream>>>(pwb, ao, proj_b, out);
}